// Round 6
// baseline (634.801 us; speedup 1.0000x reference)
//
#include <hip/hip_runtime.h>

namespace {

typedef __attribute__((ext_vector_type(8))) short short8;   // MFMA A/B frag (8 bf16)
typedef __attribute__((ext_vector_type(4))) float floatx4;  // MFMA C/D frag

constexpr int T    = 512;
constexpr int H    = 64;
constexpr int TPB  = 512;   // 8 waves -> 2 per SIMD (the R5 fix: overlap the serial chain)
constexpr int MB   = 32;    // 2 independent 16-batch groups per block
constexpr int HBU  = 144;   // h-ext row stride (ushorts): 128 data + 16 pad
                            //   dword stride 72 -> bank quad (2n+kg)&7: 8 lanes/quad, balanced
constexpr int XSTR = 516;   // xs row stride (floats)
constexpr int FSTR = 68;    // hf32 row stride (floats)

__device__ __forceinline__ ushort f2bf(float x) {  // fp32 -> bf16 RN-even (finite inputs)
  unsigned u = __float_as_uint(x);
  unsigned r = u + 0x7fffu + ((u >> 16) & 1u);
  return (ushort)(r >> 16);
}
__device__ __forceinline__ float bf2f(ushort h) {
  return __uint_as_float(((unsigned)h) << 16);
}
__device__ __forceinline__ float fsig(float x) {
  return __builtin_amdgcn_rcpf(1.0f + __expf(-x));
}
__device__ __forceinline__ float ftanh(float x) {
  return fmaf(-2.0f, __builtin_amdgcn_rcpf(1.0f + __expf(2.0f * x)), 1.0f);
}

// Per step, per 16-batch group: D = W_ext * h_ext + (bias + x*W_ih), via
// 16x16x32 bf16 MFMA, 3-term fp32 split: Whi*hhi + Whi*hlo + Wlo*hhi (6 MFMA).
// (R5 bug fixed: the Wlo*hhi B-operand IS f0/f1 — no duplicate region.)
// Layouts (verified R5, absmax 3e-5): A[m=lane&15][k=8*(lane>>4)+j];
// B[k=8*(lane>>4)+j][n=lane&15]; D col=lane&15 (batch), row=4*(lane>>4)+reg.
// Wave wj owns N-tiles {wj, wj+4, wj+8, wj+12} -> lane holds i,f,g,o of units
// 16wj+4kg+[0,4), one batch. Waves 0-3: batches [0,16); waves 4-7: [16,32).
__global__ __launch_bounds__(TPB, 1)
void lstm_mfma(const float* __restrict__ xg,
               const float* __restrict__ W_ih,
               const float* __restrict__ W_hh,
               const float* __restrict__ b_ih,
               const float* __restrict__ b_hh,
               const float* __restrict__ fc1_w,
               const float* __restrict__ fc1_b,
               const float* __restrict__ fc2_w,
               const float* __restrict__ fc2_b,
               float* __restrict__ out)
{
  __shared__ __align__(16) ushort hA[MB * HBU];   // h-ext bf16 double-buffer
  __shared__ __align__(16) ushort hB[MB * HBU];   // row: [0,64)=hi, [64,128)=lo, [128,144) pad
  __shared__ __align__(16) float  xs[MB * XSTR];
  __shared__ __align__(16) float  hf[MB * FSTR];  // final h fp32 (head input; written once)
  __shared__ float zs[MB][16];

  const int tid  = threadIdx.x;
  const int b0   = blockIdx.x * MB;
  const int lane = tid & 63;
  const int wv   = tid >> 6;     // 0..7
  const int g2   = wv >> 2;      // batch group 0/1
  const int wj   = wv & 3;       // N-tile set within group
  const int n    = lane & 15;    // batch col (B/D), A-frag row
  const int kg   = lane >> 4;    // k-group (A/B), row-quad (D)
  const int brow = 16 * g2 + n;  // batch row in LDS (0..31)

  // ---- stage x (coalesced float4) ----
  for (int i = tid; i < MB * T / 4; i += TPB) {
    const int xb = i >> 7, tq = i & 127;
    float4 v = ((const float4*)(xg + (size_t)(b0 + xb) * T))[tq];
    *(float4*)&xs[xb * XSTR + tq * 4] = v;
  }
  // ---- zero h buffers (h0 = 0) ----
  for (int i = tid; i < MB * HBU; i += TPB) { hA[i] = 0; hB[i] = 0; }

  // ---- static W fragments (identical for both groups) ----
  short8 whi0[4], whi1[4], wlo0[4], wlo1[4];
  float bia[4][4], wih[4][4];
#pragma unroll
  for (int g = 0; g < 4; ++g) {
    const int arow = 64 * g + 16 * wj + n;          // this lane's A-frag row
    const float* wr = W_hh + arow * H + 8 * kg;     // k slice [8kg,8kg+8) and +32
    const float4 p0 = *(const float4*)(wr + 0);
    const float4 p1 = *(const float4*)(wr + 4);
    const float4 p2 = *(const float4*)(wr + 32);
    const float4 p3 = *(const float4*)(wr + 36);
    const float v0[8] = {p0.x, p0.y, p0.z, p0.w, p1.x, p1.y, p1.z, p1.w};
    const float v1[8] = {p2.x, p2.y, p2.z, p2.w, p3.x, p3.y, p3.z, p3.w};
#pragma unroll
    for (int j = 0; j < 8; ++j) {
      const ushort h0 = f2bf(v0[j]);
      whi0[g][j] = (short)h0;
      wlo0[g][j] = (short)f2bf(v0[j] - bf2f(h0));   // exact remainder, then RN
      const ushort h1 = f2bf(v1[j]);
      whi1[g][j] = (short)h1;
      wlo1[g][j] = (short)f2bf(v1[j] - bf2f(h1));
    }
    const int drow = 64 * g + 16 * wj + 4 * kg;     // this lane's D rows (+r)
#pragma unroll
    for (int r = 0; r < 4; ++r) {
      bia[g][r] = b_ih[drow + r] + b_hh[drow + r];
      wih[g][r] = W_ih[drow + r];
    }
  }

  const int Ubase = 16 * wj + 4 * kg;   // this lane's 4 units
  float c[4] = {0.0f, 0.0f, 0.0f, 0.0f};
  float4 hkeep = make_float4(0.f, 0.f, 0.f, 0.f);
  const float* xq = &xs[brow * XSTR];

  __syncthreads();

#define STEP(HR, HW, TT)                                                       \
  {                                                                            \
    const float xt = xq[(TT)];                                                 \
    floatx4 acc[4];                                                            \
    _Pragma("unroll") for (int g = 0; g < 4; ++g)                              \
      _Pragma("unroll") for (int r = 0; r < 4; ++r)                            \
        acc[g][r] = fmaf(xt, wih[g][r], bia[g][r]);                            \
    const ushort* hb = (HR) + brow * HBU + 8 * kg;                             \
    const short8 f0 = *(const short8*)(hb + 0);    /* h_hi k 0..31  */         \
    const short8 f1 = *(const short8*)(hb + 32);   /* h_hi k 32..63 */         \
    const short8 f2 = *(const short8*)(hb + 64);   /* h_lo k 0..31  */         \
    const short8 f3 = *(const short8*)(hb + 96);   /* h_lo k 32..63 */         \
    _Pragma("unroll") for (int g = 0; g < 4; ++g) {                            \
      acc[g] = __builtin_amdgcn_mfma_f32_16x16x32_bf16(whi0[g], f0, acc[g], 0, 0, 0); \
      acc[g] = __builtin_amdgcn_mfma_f32_16x16x32_bf16(whi1[g], f1, acc[g], 0, 0, 0); \
      acc[g] = __builtin_amdgcn_mfma_f32_16x16x32_bf16(whi0[g], f2, acc[g], 0, 0, 0); \
      acc[g] = __builtin_amdgcn_mfma_f32_16x16x32_bf16(whi1[g], f3, acc[g], 0, 0, 0); \
      acc[g] = __builtin_amdgcn_mfma_f32_16x16x32_bf16(wlo0[g], f0, acc[g], 0, 0, 0); \
      acc[g] = __builtin_amdgcn_mfma_f32_16x16x32_bf16(wlo1[g], f1, acc[g], 0, 0, 0); \
    }                                                                          \
    float hnew[4];                                                             \
    _Pragma("unroll") for (int r = 0; r < 4; ++r) {                            \
      const float ig = fsig(acc[0][r]);                                        \
      const float fg = fsig(acc[1][r]);                                        \
      const float gg = ftanh(acc[2][r]);                                       \
      const float og = fsig(acc[3][r]);                                        \
      c[r] = fmaf(fg, c[r], ig * gg);                                          \
      hnew[r] = og * ftanh(c[r]);                                              \
    }                                                                          \
    const ushort u0 = f2bf(hnew[0]), u1 = f2bf(hnew[1]);                       \
    const ushort u2 = f2bf(hnew[2]), u3 = f2bf(hnew[3]);                       \
    ushort* hw = (HW) + brow * HBU + Ubase;                                    \
    *(ushort4*)(hw + 0)  = make_ushort4(u0, u1, u2, u3);                       \
    *(ushort4*)(hw + 64) = make_ushort4(f2bf(hnew[0] - bf2f(u0)),              \
                                        f2bf(hnew[1] - bf2f(u1)),              \
                                        f2bf(hnew[2] - bf2f(u2)),              \
                                        f2bf(hnew[3] - bf2f(u3)));             \
    hkeep = make_float4(hnew[0], hnew[1], hnew[2], hnew[3]);                   \
    __syncthreads();                                                           \
  }

  for (int t = 0; t < T; t += 2) {
    STEP(hA, hB, t);
    STEP(hB, hA, t + 1);
  }
#undef STEP

  // ---- final h (fp32, from registers) -> LDS once; then the head ----
  *(float4*)&hf[brow * FSTR + Ubase] = hkeep;
  __syncthreads();
  {
    const int bq = tid >> 4, j2 = tid & 15;   // 32 batches x 16 hidden2 = 512 threads
    float s = fc1_b[j2];
    const float* fw = fc1_w + j2 * H;
#pragma unroll
    for (int k = 0; k < H; ++k) s = fmaf(hf[bq * FSTR + k], fw[k], s);
    s = fmaxf(s, 0.0f);
    zs[bq][j2] = s * fc2_w[j2];
  }
  __syncthreads();
  if (tid < MB) {
    float s = fc2_b[0];
#pragma unroll
    for (int j = 0; j < 16; ++j) s += zs[tid][j];
    out[b0 + tid] = s;
  }
}

}  // namespace

extern "C" void kernel_launch(void* const* d_in, const int* in_sizes, int n_in,
                              void* d_out, int out_size, void* d_ws, size_t ws_size,
                              hipStream_t stream) {
  const float* xg    = (const float*)d_in[0];
  const float* W_ih  = (const float*)d_in[1];
  const float* W_hh  = (const float*)d_in[2];
  const float* b_ih  = (const float*)d_in[3];
  const float* b_hh  = (const float*)d_in[4];
  const float* fc1_w = (const float*)d_in[5];
  const float* fc1_b = (const float*)d_in[6];
  const float* fc2_w = (const float*)d_in[7];
  const float* fc2_b = (const float*)d_in[8];
  float* out = (float*)d_out;

  dim3 grid(2048 / MB);   // 64 blocks, 1 per CU, 8 waves = 2/SIMD
  dim3 block(TPB);
  hipLaunchKernelGGL(lstm_mfma, grid, block, 0, stream,
                     xg, W_ih, W_hh, b_ih, b_hh, fc1_w, fc1_b, fc2_w, fc2_b, out);
}

// Round 7
// 440.672 us; speedup vs baseline: 1.4405x; 1.4405x over previous
//
#include <hip/hip_runtime.h>

namespace {

typedef __attribute__((ext_vector_type(8))) short short8;   // MFMA A/B frag (8 bf16)
typedef __attribute__((ext_vector_type(4))) float floatx4;  // MFMA C/D frag

constexpr int T    = 512;
constexpr int H    = 64;
constexpr int TPB  = 256;   // 4 waves (R5 topology: 128 blocks = the CU cap for 16-batch groups)
constexpr int MB   = 16;
constexpr int HBU  = 136;   // h-ext row stride (ushorts): 128 data + 8 pad
                            //   272B/row -> 17 bank-quads -> quad (17n+kg)&7 = (n+kg)&7: balanced
constexpr int XSTR = 516;   // xs row stride (floats); +4 pad also covers xq[T] prefetch read
constexpr int FSTR = 68;    // hf32 row stride (floats, head only)

__device__ __forceinline__ ushort f2bf(float x) {  // fp32 -> bf16 RN-even (finite inputs)
  unsigned u = __float_as_uint(x);
  unsigned r = u + 0x7fffu + ((u >> 16) & 1u);
  return (ushort)(r >> 16);
}
__device__ __forceinline__ float bf2f(ushort h) {
  return __uint_as_float(((unsigned)h) << 16);
}
__device__ __forceinline__ float fsig(float x) {
  return __builtin_amdgcn_rcpf(1.0f + __expf(-x));
}
__device__ __forceinline__ float ftanh(float x) {
  return fmaf(-2.0f, __builtin_amdgcn_rcpf(1.0f + __expf(2.0f * x)), 1.0f);
}

// Per step: D = W_ext*h_ext + (bias + x*W_ih), 16x16x32 bf16 MFMA, 3-term split.
// R7 changes vs R5/R6 (chain-latency cuts; R5/R6 counters show SIMDs ~70% idle
// on a serial chain, largest suspect = dependent-MFMA latency):
//  - each gate's 6-deep MFMA chain -> two parallel 3-deep chains + vector add
//  - acc-init (bias + x*W_ih) for step t+1 computed during step t (off-chain)
// Layouts (verified R5): A[m=lane&15][k=8*(lane>>4)+j]; B[k][n=lane&15];
// D col=lane&15 (batch), row=4*(lane>>4)+reg. Wave wj owns N-tiles
// {wj,wj+4,wj+8,wj+12} -> lane holds i,f,g,o of units 16wj+4kg+[0,4), one batch.
__global__ __launch_bounds__(TPB, 1)
void lstm_mfma(const float* __restrict__ xg,
               const float* __restrict__ W_ih,
               const float* __restrict__ W_hh,
               const float* __restrict__ b_ih,
               const float* __restrict__ b_hh,
               const float* __restrict__ fc1_w,
               const float* __restrict__ fc1_b,
               const float* __restrict__ fc2_w,
               const float* __restrict__ fc2_b,
               float* __restrict__ out)
{
  __shared__ __align__(16) ushort hA[MB * HBU];   // h-ext bf16 double-buffer
  __shared__ __align__(16) ushort hB[MB * HBU];   // row: [0,64)=hi, [64,128)=lo, pad
  __shared__ __align__(16) float  xs[MB * XSTR];
  __shared__ __align__(16) float  hf[MB * FSTR];  // final h fp32 (head; written once)
  __shared__ float zs[MB][16];

  const int tid  = threadIdx.x;
  const int b0   = blockIdx.x * MB;
  const int lane = tid & 63;
  const int wj   = tid >> 6;     // wave 0..3
  const int n    = lane & 15;    // batch col (B/D), A-frag row
  const int kg   = lane >> 4;    // k-group (A/B), row-quad (D)

  // ---- stage x (coalesced float4) ----
  for (int i = tid; i < MB * T / 4; i += TPB) {
    const int xb = i >> 7, tq = i & 127;
    float4 v = ((const float4*)(xg + (size_t)(b0 + xb) * T))[tq];
    *(float4*)&xs[xb * XSTR + tq * 4] = v;
  }
  // ---- zero h buffers (h0 = 0) ----
  for (int i = tid; i < MB * HBU; i += TPB) { hA[i] = 0; hB[i] = 0; }

  // ---- static W fragments ----
  short8 whi0[4], whi1[4], wlo0[4], wlo1[4];
  float bia[4][4], wih[4][4];
#pragma unroll
  for (int g = 0; g < 4; ++g) {
    const int arow = 64 * g + 16 * wj + n;          // this lane's A-frag row
    const float* wr = W_hh + arow * H + 8 * kg;     // k slice [8kg,8kg+8) and +32
    const float4 p0 = *(const float4*)(wr + 0);
    const float4 p1 = *(const float4*)(wr + 4);
    const float4 p2 = *(const float4*)(wr + 32);
    const float4 p3 = *(const float4*)(wr + 36);
    const float v0[8] = {p0.x, p0.y, p0.z, p0.w, p1.x, p1.y, p1.z, p1.w};
    const float v1[8] = {p2.x, p2.y, p2.z, p2.w, p3.x, p3.y, p3.z, p3.w};
#pragma unroll
    for (int j = 0; j < 8; ++j) {
      const ushort h0 = f2bf(v0[j]);
      whi0[g][j] = (short)h0;
      wlo0[g][j] = (short)f2bf(v0[j] - bf2f(h0));   // exact remainder, then RN
      const ushort h1 = f2bf(v1[j]);
      whi1[g][j] = (short)h1;
      wlo1[g][j] = (short)f2bf(v1[j] - bf2f(h1));
    }
    const int drow = 64 * g + 16 * wj + 4 * kg;     // this lane's D rows (+r)
#pragma unroll
    for (int r = 0; r < 4; ++r) {
      bia[g][r] = b_ih[drow + r] + b_hh[drow + r];
      wih[g][r] = W_ih[drow + r];
    }
  }

  const int Ubase = 16 * wj + 4 * kg;   // this lane's 4 units
  float c[4] = {0.0f, 0.0f, 0.0f, 0.0f};
  float4 hkeep = make_float4(0.f, 0.f, 0.f, 0.f);
  const float* xq = &xs[n * XSTR];

  __syncthreads();

  // acc-init for t=0 (x is staged; safe to read after the barrier above)
  floatx4 init[4];
  {
    const float x0 = xq[0];
#pragma unroll
    for (int g = 0; g < 4; ++g)
#pragma unroll
      for (int r = 0; r < 4; ++r) init[g][r] = fmaf(x0, wih[g][r], bia[g][r]);
  }

#define STEP(HR, HW, TT)                                                       \
  {                                                                            \
    const ushort* hb = (HR) + n * HBU + 8 * kg;                                \
    const short8 f0 = *(const short8*)(hb + 0);    /* h_hi k 0..31  */         \
    const short8 f1 = *(const short8*)(hb + 32);   /* h_hi k 32..63 */         \
    const short8 f2 = *(const short8*)(hb + 64);   /* h_lo k 0..31  */         \
    const short8 f3 = *(const short8*)(hb + 96);   /* h_lo k 32..63 */         \
    floatx4 accA[4], accB[4];                                                  \
    const floatx4 zf = {0.f, 0.f, 0.f, 0.f};                                   \
    _Pragma("unroll") for (int g = 0; g < 4; ++g) {                            \
      /* two parallel 3-deep chains per gate (cuts dep-latency ~2x) */         \
      accA[g] = __builtin_amdgcn_mfma_f32_16x16x32_bf16(whi0[g], f0, init[g], 0, 0, 0); \
      accB[g] = __builtin_amdgcn_mfma_f32_16x16x32_bf16(wlo0[g], f0, zf,      0, 0, 0); \
      accA[g] = __builtin_amdgcn_mfma_f32_16x16x32_bf16(whi1[g], f1, accA[g], 0, 0, 0); \
      accB[g] = __builtin_amdgcn_mfma_f32_16x16x32_bf16(wlo1[g], f1, accB[g], 0, 0, 0); \
      accA[g] = __builtin_amdgcn_mfma_f32_16x16x32_bf16(whi0[g], f2, accA[g], 0, 0, 0); \
      accB[g] = __builtin_amdgcn_mfma_f32_16x16x32_bf16(whi1[g], f3, accB[g], 0, 0, 0); \
    }                                                                          \
    /* next step's acc-init: h-independent, fills MFMA stall cycles */         \
    {                                                                          \
      const float x1 = xq[(TT) + 1];                                           \
      _Pragma("unroll") for (int g = 0; g < 4; ++g)                            \
        _Pragma("unroll") for (int r = 0; r < 4; ++r)                          \
          init[g][r] = fmaf(x1, wih[g][r], bia[g][r]);                         \
    }                                                                          \
    float hnew[4];                                                             \
    _Pragma("unroll") for (int r = 0; r < 4; ++r) {                            \
      const float ig = fsig(accA[0][r] + accB[0][r]);                          \
      const float fg = fsig(accA[1][r] + accB[1][r]);                          \
      const float gg = ftanh(accA[2][r] + accB[2][r]);                         \
      const float og = fsig(accA[3][r] + accB[3][r]);                          \
      c[r] = fmaf(fg, c[r], ig * gg);                                          \
      hnew[r] = og * ftanh(c[r]);                                              \
    }                                                                          \
    const ushort u0 = f2bf(hnew[0]), u1 = f2bf(hnew[1]);                       \
    const ushort u2 = f2bf(hnew[2]), u3 = f2bf(hnew[3]);                       \
    ushort* hw = (HW) + n * HBU + Ubase;                                       \
    *(ushort4*)(hw + 0)  = make_ushort4(u0, u1, u2, u3);                       \
    *(ushort4*)(hw + 64) = make_ushort4(f2bf(hnew[0] - bf2f(u0)),              \
                                        f2bf(hnew[1] - bf2f(u1)),              \
                                        f2bf(hnew[2] - bf2f(u2)),              \
                                        f2bf(hnew[3] - bf2f(u3)));             \
    hkeep = make_float4(hnew[0], hnew[1], hnew[2], hnew[3]);                   \
    __syncthreads();                                                           \
  }

  for (int t = 0; t < T; t += 2) {
    STEP(hA, hB, t);
    STEP(hB, hA, t + 1);
  }
#undef STEP

  // ---- final h (fp32, from registers) -> LDS once; then the head ----
  *(float4*)&hf[n * FSTR + Ubase] = hkeep;
  __syncthreads();
  {
    const int bq = tid >> 4, j2 = tid & 15;   // 16 batches x 16 hidden2 = 256 threads
    float s = fc1_b[j2];
    const float* fw = fc1_w + j2 * H;
#pragma unroll
    for (int k = 0; k < H; ++k) s = fmaf(hf[bq * FSTR + k], fw[k], s);
    s = fmaxf(s, 0.0f);
    zs[bq][j2] = s * fc2_w[j2];
  }
  __syncthreads();
  if (tid < MB) {
    float s = fc2_b[0];
#pragma unroll
    for (int j = 0; j < 16; ++j) s += zs[tid][j];
    out[b0 + tid] = s;
  }
}

}  // namespace

extern "C" void kernel_launch(void* const* d_in, const int* in_sizes, int n_in,
                              void* d_out, int out_size, void* d_ws, size_t ws_size,
                              hipStream_t stream) {
  const float* xg    = (const float*)d_in[0];
  const float* W_ih  = (const float*)d_in[1];
  const float* W_hh  = (const float*)d_in[2];
  const float* b_ih  = (const float*)d_in[3];
  const float* b_hh  = (const float*)d_in[4];
  const float* fc1_w = (const float*)d_in[5];
  const float* fc1_b = (const float*)d_in[6];
  const float* fc2_w = (const float*)d_in[7];
  const float* fc2_b = (const float*)d_in[8];
  float* out = (float*)d_out;

  dim3 grid(2048 / MB);   // 128 blocks (the CU cap: 128 independent 16-batch groups)
  dim3 block(TPB);
  hipLaunchKernelGGL(lstm_mfma, grid, block, 0, stream,
                     xg, W_ih, W_hh, b_ih, b_hh, fc1_w, fc1_b, fc2_w, fc2_b, out);
}

// Round 9
// 316.130 us; speedup vs baseline: 2.0080x; 1.3940x over previous
//
#include <hip/hip_runtime.h>

namespace {

typedef __attribute__((ext_vector_type(8))) short short8;   // MFMA A/B frag (8 bf16)
typedef __attribute__((ext_vector_type(4))) float floatx4;  // MFMA C/D frag

constexpr int T    = 512;
constexpr int H    = 64;
constexpr int TPB  = 256;   // 4 waves
constexpr int MB   = 8;     // 8 batches per block -> 256 blocks = all 256 CUs
constexpr int HBU  = 144;   // h row stride (ushorts): [0,64)=hi, [72,136)=lo, pads
constexpr int LOFF = 72;    // lo-region offset (ushorts; 16B-aligned, bank-staggered)
constexpr int XSTR = 516;   // xs row stride (floats)
constexpr int FSTR = 68;    // hf32 row stride (floats, head only)

constexpr int DPP_ROR8 = 0x128;  // row_ror:8 -> lane i reads lane (i+8)&15 == i^8

__device__ __forceinline__ ushort f2bf(float x) {  // fp32 -> bf16 RN-even (finite inputs)
  unsigned u = __float_as_uint(x);
  unsigned r = u + 0x7fffu + ((u >> 16) & 1u);
  return (ushort)(r >> 16);
}
__device__ __forceinline__ float bf2f(ushort h) {
  return __uint_as_float(((unsigned)h) << 16);
}
__device__ __forceinline__ float fsig(float x) {
  return __builtin_amdgcn_rcpf(1.0f + __expf(-x));
}
__device__ __forceinline__ float ftanh(float x) {
  return fmaf(-2.0f, __builtin_amdgcn_rcpf(1.0f + __expf(2.0f * x)), 1.0f);
}
__device__ __forceinline__ float swz8(float v) {   // value from lane^8 (within row of 16)
  return __int_as_float(__builtin_amdgcn_update_dpp(
      0, __float_as_int(v), DPP_ROR8, 0xf, 0xf, true));
}

// Col-packed split GEMM per step:
//   B cols 0-7 = h_hi(batch 0-7), cols 8-15 = h_lo(batch 0-7).
//   Per gate: D1 = Whi x B (K=64, 2 MFMA), D2 = Wlo x B (2 MFMA).
//   gate[row][b] = D1[row,b]+D2[row,b]+D1[row,b+8]+D2[row,b+8] (4-term fp32 split).
// R8 BUG / R9 FIX: lane n owns rows 4kg+2*(n>>3)+{0,1}; its partner (lane n^8)
// owns the OTHER row pair. The exchange must send the PARTNER'S rows evaluated
// at THIS lane's column (snd), not this lane's own rows:
//   own = d[2*nhi + r] (my rows, my col); snd = d[2*(1-nhi) + r] (partner rows, my col)
//   gate = own + swz8(snd).
// Layouts (verified R5): A[m=lane&15][k=8*(lane>>4)+j]; B[k][n=lane&15];
// D col=lane&15, row=4*(lane>>4)+reg. Wave wj owns W_ext row-tiles {wj,wj+4,wj+8,wj+12}.
__global__ __launch_bounds__(TPB, 1)
void lstm_mfma(const float* __restrict__ xg,
               const float* __restrict__ W_ih,
               const float* __restrict__ W_hh,
               const float* __restrict__ b_ih,
               const float* __restrict__ b_hh,
               const float* __restrict__ fc1_w,
               const float* __restrict__ fc1_b,
               const float* __restrict__ fc2_w,
               const float* __restrict__ fc2_b,
               float* __restrict__ out)
{
  __shared__ __align__(16) ushort hA[MB * HBU];   // h double-buffer (hi | lo regions)
  __shared__ __align__(16) ushort hB[MB * HBU];
  __shared__ __align__(16) float  xs[MB * XSTR];
  __shared__ __align__(16) float  hf[MB * FSTR];  // final h fp32 (head; written once)
  __shared__ float zs[MB][16];

  const int tid  = threadIdx.x;
  const int b0   = blockIdx.x * MB;
  const int lane = tid & 63;
  const int wj   = tid >> 6;       // wave 0..3
  const int n    = lane & 15;      // MFMA col; batch = n&7, half = n>>3
  const int kg   = lane >> 4;      // k-group (A/B), row-quad (D)
  const int bat  = n & 7;
  const int nhi  = n >> 3;         // 0: owns rows 4kg+{0,1}; 1: rows 4kg+{2,3}
  const int roff = 2 * nhi;

  // ---- stage x (coalesced float4) ----
  for (int i = tid; i < MB * T / 4; i += TPB) {
    const int xb = i >> 7, tq = i & 127;
    float4 v = ((const float4*)(xg + (size_t)(b0 + xb) * T))[tq];
    *(float4*)&xs[xb * XSTR + tq * 4] = v;
  }
  // ---- zero h buffers (h0 = 0; pads stay 0) ----
  for (int i = tid; i < MB * HBU; i += TPB) { hA[i] = 0; hB[i] = 0; }

  // ---- static W fragments (A-operands; layout verified R5) ----
  short8 whi0[4], whi1[4], wlo0[4], wlo1[4];
#pragma unroll
  for (int g = 0; g < 4; ++g) {
    const int arow = 64 * g + 16 * wj + n;          // this lane's A-frag row
    const float* wr = W_hh + arow * H + 8 * kg;     // k slice [8kg,8kg+8) and +32
    const float4 p0 = *(const float4*)(wr + 0);
    const float4 p1 = *(const float4*)(wr + 4);
    const float4 p2 = *(const float4*)(wr + 32);
    const float4 p3 = *(const float4*)(wr + 36);
    const float v0[8] = {p0.x, p0.y, p0.z, p0.w, p1.x, p1.y, p1.z, p1.w};
    const float v1[8] = {p2.x, p2.y, p2.z, p2.w, p3.x, p3.y, p3.z, p3.w};
#pragma unroll
    for (int j = 0; j < 8; ++j) {
      const ushort h0 = f2bf(v0[j]);
      whi0[g][j] = (short)h0;
      wlo0[g][j] = (short)f2bf(v0[j] - bf2f(h0));   // exact remainder, then RN
      const ushort h1 = f2bf(v1[j]);
      whi1[g][j] = (short)h1;
      wlo1[g][j] = (short)f2bf(v1[j] - bf2f(h1));
    }
  }
  // bias + W_ih for the 2 owned rows per gate
  float bia[4][2], wih[4][2];
#pragma unroll
  for (int g = 0; g < 4; ++g) {
    const int drow = 64 * g + 16 * wj + 4 * kg + roff;
#pragma unroll
    for (int j = 0; j < 2; ++j) {
      bia[g][j] = b_ih[drow + j] + b_hh[drow + j];
      wih[g][j] = W_ih[drow + j];
    }
  }

  const int rdoff = bat * HBU + LOFF * nhi + 8 * kg;         // B-frag read base
  const int wroff = bat * HBU + (16 * wj + 4 * kg + roff);   // h write base (hi)
  const float* xq = &xs[bat * XSTR];
  float cA = 0.0f, cB = 0.0f;          // c-state for the 2 owned (unit,batch) pairs
  float hkA = 0.0f, hkB = 0.0f;        // final-h keep

  __syncthreads();

#define STEP(HR, HW, TT)                                                       \
  {                                                                            \
    const ushort* hb = (HR) + rdoff;                                           \
    const short8 f0 = *(const short8*)(hb + 0);    /* k 0..31  (hi or lo) */   \
    const short8 f1 = *(const short8*)(hb + 32);   /* k 32..63 */              \
    const floatx4 zf = {0.f, 0.f, 0.f, 0.f};                                   \
    const float xt = xq[(TT)];                                                 \
    float g0[4], g1[4];   /* owned-row gate values, pre-activation */          \
    _Pragma("unroll") for (int g = 0; g < 4; ++g) {                            \
      floatx4 d1 = __builtin_amdgcn_mfma_f32_16x16x32_bf16(whi0[g], f0, zf, 0, 0, 0); \
      floatx4 d2 = __builtin_amdgcn_mfma_f32_16x16x32_bf16(wlo0[g], f0, zf, 0, 0, 0); \
      d1 = __builtin_amdgcn_mfma_f32_16x16x32_bf16(whi1[g], f1, d1, 0, 0, 0);  \
      d2 = __builtin_amdgcn_mfma_f32_16x16x32_bf16(wlo1[g], f1, d2, 0, 0, 0);  \
      /* own rows @ my col; partner's rows @ my col (to send) */               \
      const float ownA = nhi ? (d1[2] + d2[2]) : (d1[0] + d2[0]);              \
      const float ownB = nhi ? (d1[3] + d2[3]) : (d1[1] + d2[1]);              \
      const float sndA = nhi ? (d1[0] + d2[0]) : (d1[2] + d2[2]);              \
      const float sndB = nhi ? (d1[1] + d2[1]) : (d1[3] + d2[3]);              \
      g0[g] = ownA + swz8(sndA) + fmaf(xt, wih[g][0], bia[g][0]);              \
      g1[g] = ownB + swz8(sndB) + fmaf(xt, wih[g][1], bia[g][1]);              \
    }                                                                          \
    const float iA = fsig(g0[0]), iB = fsig(g1[0]);                            \
    const float fA = fsig(g0[1]), fB = fsig(g1[1]);                            \
    const float gA = ftanh(g0[2]), gB = ftanh(g1[2]);                          \
    const float oA = fsig(g0[3]), oB = fsig(g1[3]);                            \
    cA = fmaf(fA, cA, iA * gA);                                                \
    cB = fmaf(fB, cB, iB * gB);                                                \
    hkA = oA * ftanh(cA);                                                      \
    hkB = oB * ftanh(cB);                                                      \
    const ushort hiA = f2bf(hkA), hiB = f2bf(hkB);                             \
    ushort* hw = (HW) + wroff;                                                 \
    *(ushort2*)(hw + 0)    = make_ushort2(hiA, hiB);                           \
    *(ushort2*)(hw + LOFF) = make_ushort2(f2bf(hkA - bf2f(hiA)),               \
                                          f2bf(hkB - bf2f(hiB)));              \
    __syncthreads();                                                           \
  }

  for (int t = 0; t < T; t += 2) {
    STEP(hA, hB, t);
    STEP(hB, hA, t + 1);
  }
#undef STEP

  // ---- final h (fp32, from registers) -> LDS once; then the head ----
  *(float2*)&hf[bat * FSTR + 16 * wj + 4 * kg + roff] = make_float2(hkA, hkB);
  __syncthreads();
  if (tid < MB * 16) {
    const int bq = tid >> 4, j2 = tid & 15;   // 8 batches x 16 hidden2
    float s = fc1_b[j2];
    const float* fw = fc1_w + j2 * H;
#pragma unroll
    for (int k = 0; k < H; ++k) s = fmaf(hf[bq * FSTR + k], fw[k], s);
    s = fmaxf(s, 0.0f);
    zs[bq][j2] = s * fc2_w[j2];
  }
  __syncthreads();
  if (tid < MB) {
    float s = fc2_b[0];
#pragma unroll
    for (int j = 0; j < 16; ++j) s += zs[tid][j];
    out[b0 + tid] = s;
  }
}

}  // namespace

extern "C" void kernel_launch(void* const* d_in, const int* in_sizes, int n_in,
                              void* d_out, int out_size, void* d_ws, size_t ws_size,
                              hipStream_t stream) {
  const float* xg    = (const float*)d_in[0];
  const float* W_ih  = (const float*)d_in[1];
  const float* W_hh  = (const float*)d_in[2];
  const float* b_ih  = (const float*)d_in[3];
  const float* b_hh  = (const float*)d_in[4];
  const float* fc1_w = (const float*)d_in[5];
  const float* fc1_b = (const float*)d_in[6];
  const float* fc2_w = (const float*)d_in[7];
  const float* fc2_b = (const float*)d_in[8];
  float* out = (float*)d_out;

  dim3 grid(2048 / MB);   // 256 blocks -> every CU hosts one 8-batch group
  dim3 block(TPB);
  hipLaunchKernelGGL(lstm_mfma, grid, block, 0, stream,
                     xg, W_ih, W_hh, b_ih, b_hh, fc1_w, fc1_b, fc2_w, fc2_b, out);
}